// Round 4
// baseline (481.340 us; speedup 1.0000x reference)
//
#include <hip/hip_runtime.h>

#define NN 100000
#define NE 1600000
#define FIN 128
#define FH 48
#define FO 32
#define NB 391                      // ceil(NN/256) scan blocks
#define NODES_PER_BLOCK 21          // 12 threads/node, 252 of 256 threads active

// ---------------- degree / normalization / CSR build ----------------

__global__ __launch_bounds__(256) void k_zero(int* __restrict__ deg_i) {
  int i = blockIdx.x * 256 + threadIdx.x;
  if (i < NN) deg_i[i] = 0;
}

__global__ __launch_bounds__(256) void k_hist(const int* __restrict__ dst, int* __restrict__ deg_i) {
  int i = blockIdx.x * 256 + threadIdx.x;
  if (i < NE) atomicAdd(&deg_i[dst[i]], 1);
}

// scan pass 1: per-block sums of deg_i (+ fused dinv = rsqrt(deg+1))
__global__ __launch_bounds__(256) void k_scan1(const int* __restrict__ deg_i, int* __restrict__ bsum,
                                               float* __restrict__ dinv) {
  __shared__ int s[256];
  int t = threadIdx.x, i = blockIdx.x * 256 + t;
  int d = (i < NN) ? deg_i[i] : 0;
  s[t] = d;
  if (i < NN) dinv[i] = rsqrtf((float)d + 1.0f);  // +1 self-loop
  __syncthreads();
  for (int o = 128; o > 0; o >>= 1) { if (t < o) s[t] += s[t + o]; __syncthreads(); }
  if (t == 0) bsum[blockIdx.x] = s[0];
}

// scan pass 2: serial exclusive scan of NB block sums (~µs)
__global__ void k_scan2(int* __restrict__ bsum, int* __restrict__ off) {
  if (threadIdx.x == 0 && blockIdx.x == 0) {
    int run = 0;
    for (int b = 0; b < NB; ++b) { int v = bsum[b]; bsum[b] = run; run += v; }
    off[NN] = run;  // == NE
  }
}

// scan pass 3: in-block Hillis-Steele -> exclusive offsets; cursor copy for binning
__global__ __launch_bounds__(256) void k_scan3(const int* __restrict__ deg_i, const int* __restrict__ bsum,
                                               int* __restrict__ off, int* __restrict__ cursor) {
  __shared__ int s[256];
  int t = threadIdx.x, i = blockIdx.x * 256 + t;
  int v = (i < NN) ? deg_i[i] : 0;
  s[t] = v;
  __syncthreads();
  for (int o = 1; o < 256; o <<= 1) {
    int a = (t >= o) ? s[t - o] : 0;
    __syncthreads();
    s[t] += a;
    __syncthreads();
  }
  int excl = s[t] - v + bsum[blockIdx.x];
  if (i < NN) { off[i] = excl; cursor[i] = excl; }
}

// bin edges by dst: csr[pos] = src   (4 B/edge; norm recomputed in gather)
__global__ __launch_bounds__(256) void k_bin(const int* __restrict__ src, const int* __restrict__ dst,
                                             int* __restrict__ cursor, int* __restrict__ csr) {
  int e = blockIdx.x * 256 + threadIdx.x;
  if (e >= NE) return;
  int d = dst[e];
  int pos = atomicAdd(&cursor[d], 1);
  csr[pos] = src[e];
}

// ---------------- layer-1 dense: t1 = x @ W1 ----------------
// 64 rows/block, x tile in LDS (pad 132), W1 (128x48) in LDS, 12 cols/thread.

__global__ __launch_bounds__(256) void k_gemm1(const float* __restrict__ x, const float* __restrict__ W1,
                                               float* __restrict__ t1) {
  __shared__ float xs[64][132];
  __shared__ float ws[FIN][FH];
  const int t = threadIdx.x;
  const int row0 = blockIdx.x * 64;

  for (int i = t; i < FIN * FH; i += 256) ws[i / FH][i % FH] = W1[i];
  for (int i = t; i < 64 * (FIN / 4); i += 256) {
    int r = i >> 5, c4 = i & 31;
    float4 v = make_float4(0.f, 0.f, 0.f, 0.f);
    if (row0 + r < NN) v = ((const float4*)x)[(size_t)(row0 + r) * (FIN / 4) + c4];
    xs[r][c4 * 4 + 0] = v.x; xs[r][c4 * 4 + 1] = v.y;
    xs[r][c4 * 4 + 2] = v.z; xs[r][c4 * 4 + 3] = v.w;
  }
  __syncthreads();

  const int row = t >> 2;
  const int cg  = (t & 3) * 12;
  float acc[12];
  #pragma unroll
  for (int j = 0; j < 12; ++j) acc[j] = 0.f;

  #pragma unroll 4
  for (int k = 0; k < FIN; ++k) {
    float xv = xs[row][k];
    const float4* wp = (const float4*)&ws[k][cg];
    float4 w0 = wp[0], w1 = wp[1], w2 = wp[2];
    acc[0] += xv * w0.x; acc[1] += xv * w0.y; acc[2]  += xv * w0.z; acc[3]  += xv * w0.w;
    acc[4] += xv * w1.x; acc[5] += xv * w1.y; acc[6]  += xv * w1.z; acc[7]  += xv * w1.w;
    acc[8] += xv * w2.x; acc[9] += xv * w2.y; acc[10] += xv * w2.z; acc[11] += xv * w2.w;
  }

  const int grow = row0 + row;
  if (grow < NN) {
    float* tp = t1 + (size_t)grow * FH + cg;
    #pragma unroll
    for (int j = 0; j < 12; ++j) tp[j] = acc[j];
  }
}

// ---------------- layer-1 gather: h = relu(dinv^2*t1[n] + sum dinv[s]*dinv[n]*t1[s] + b1) ----------------
// 12 threads per node (one float4 lane each); atomic-free.

__global__ __launch_bounds__(256) void k_gather1(const int* __restrict__ off, const int* __restrict__ csr,
                                                 const float* __restrict__ feat, const float* __restrict__ dinv,
                                                 const float* __restrict__ bias, float* __restrict__ out) {
  const int t = threadIdx.x;
  if (t >= NODES_PER_BLOCK * 12) return;
  const int local = t / 12;
  const int f4 = t - local * 12;
  const int node = blockIdx.x * NODES_PER_BLOCK + local;
  if (node >= NN) return;

  const float4* feat4 = (const float4*)feat;
  const float di = dinv[node];
  const float sn = di * di;
  float4 v = feat4[(size_t)node * 12 + f4];
  float4 acc = make_float4(v.x * sn, v.y * sn, v.z * sn, v.w * sn);

  int j = off[node];
  const int jend = off[node + 1];
  for (; j + 4 <= jend; j += 4) {
    int s0 = csr[j], s1 = csr[j + 1], s2 = csr[j + 2], s3 = csr[j + 3];
    float n0 = dinv[s0] * di, n1 = dinv[s1] * di, n2 = dinv[s2] * di, n3 = dinv[s3] * di;
    float4 v0 = feat4[(size_t)s0 * 12 + f4];
    float4 v1 = feat4[(size_t)s1 * 12 + f4];
    float4 v2 = feat4[(size_t)s2 * 12 + f4];
    float4 v3 = feat4[(size_t)s3 * 12 + f4];
    acc.x += n0 * v0.x; acc.y += n0 * v0.y; acc.z += n0 * v0.z; acc.w += n0 * v0.w;
    acc.x += n1 * v1.x; acc.y += n1 * v1.y; acc.z += n1 * v1.z; acc.w += n1 * v1.w;
    acc.x += n2 * v2.x; acc.y += n2 * v2.y; acc.z += n2 * v2.z; acc.w += n2 * v2.w;
    acc.x += n3 * v3.x; acc.y += n3 * v3.y; acc.z += n3 * v3.z; acc.w += n3 * v3.w;
  }
  for (; j < jend; ++j) {
    int s = csr[j];
    float nv = dinv[s] * di;
    float4 vv = feat4[(size_t)s * 12 + f4];
    acc.x += nv * vv.x; acc.y += nv * vv.y; acc.z += nv * vv.z; acc.w += nv * vv.w;
  }

  const float4 bb = ((const float4*)bias)[f4];
  acc.x = fmaxf(acc.x + bb.x, 0.f);
  acc.y = fmaxf(acc.y + bb.y, 0.f);
  acc.z = fmaxf(acc.z + bb.z, 0.f);
  acc.w = fmaxf(acc.w + bb.w, 0.f);
  ((float4*)out)[(size_t)node * 12 + f4] = acc;
}

// ---------------- layer-2 fused: agg = Ahat*h (registers) -> LDS -> out = agg@[Wmu|Wls] + [bmu|bls] ----------------

__global__ __launch_bounds__(256) void k_gather_gemm2(const int* __restrict__ off, const int* __restrict__ csr,
                                                      const float* __restrict__ feat, const float* __restrict__ dinv,
                                                      const float* __restrict__ Wmu, const float* __restrict__ bmu,
                                                      const float* __restrict__ Wls, const float* __restrict__ bls,
                                                      float* __restrict__ out) {
  __shared__ float wall[FH][2 * FO];             // [48][64]: mu cols 0..31, ls cols 32..63
  __shared__ float as2[NODES_PER_BLOCK][FH + 1]; // 21 x 49 (pad: broadcast reads anyway)
  const int t = threadIdx.x;

  for (int i = t; i < FH * 2 * FO; i += 256) {
    int k = i >> 6, c = i & 63;
    wall[k][c] = (c < FO) ? Wmu[k * FO + c] : Wls[k * FO + (c - FO)];
  }

  const int local = t / 12;
  const int f4 = t - local * 12;
  const int node = blockIdx.x * NODES_PER_BLOCK + local;
  const bool active = (local < NODES_PER_BLOCK) && (node < NN);

  if (active) {
    const float4* feat4 = (const float4*)feat;
    const float di = dinv[node];
    const float sn = di * di;
    float4 v = feat4[(size_t)node * 12 + f4];
    float4 acc = make_float4(v.x * sn, v.y * sn, v.z * sn, v.w * sn);

    int j = off[node];
    const int jend = off[node + 1];
    for (; j + 4 <= jend; j += 4) {
      int s0 = csr[j], s1 = csr[j + 1], s2 = csr[j + 2], s3 = csr[j + 3];
      float n0 = dinv[s0] * di, n1 = dinv[s1] * di, n2 = dinv[s2] * di, n3 = dinv[s3] * di;
      float4 v0 = feat4[(size_t)s0 * 12 + f4];
      float4 v1 = feat4[(size_t)s1 * 12 + f4];
      float4 v2 = feat4[(size_t)s2 * 12 + f4];
      float4 v3 = feat4[(size_t)s3 * 12 + f4];
      acc.x += n0 * v0.x; acc.y += n0 * v0.y; acc.z += n0 * v0.z; acc.w += n0 * v0.w;
      acc.x += n1 * v1.x; acc.y += n1 * v1.y; acc.z += n1 * v1.z; acc.w += n1 * v1.w;
      acc.x += n2 * v2.x; acc.y += n2 * v2.y; acc.z += n2 * v2.z; acc.w += n2 * v2.w;
      acc.x += n3 * v3.x; acc.y += n3 * v3.y; acc.z += n3 * v3.z; acc.w += n3 * v3.w;
    }
    for (; j < jend; ++j) {
      int s = csr[j];
      float nv = dinv[s] * di;
      float4 vv = feat4[(size_t)s * 12 + f4];
      acc.x += nv * vv.x; acc.y += nv * vv.y; acc.z += nv * vv.z; acc.w += nv * vv.w;
    }

    float* ap = &as2[local][f4 * 4];
    ap[0] = acc.x; ap[1] = acc.y; ap[2] = acc.z; ap[3] = acc.w;
  }
  __syncthreads();

  // gemm phase: 21 nodes x 64 outputs = 1344, strided over 256 threads
  for (int o = t; o < NODES_PER_BLOCK * 2 * FO; o += 256) {
    const int ln = o >> 6;
    const int c = o & 63;
    const int grow = blockIdx.x * NODES_PER_BLOCK + ln;
    if (grow < NN) {
      float a = (c < FO) ? bmu[c] : bls[c - FO];
      #pragma unroll
      for (int k = 0; k < FH; ++k) a += as2[ln][k] * wall[k][c];
      if (c < FO) out[(size_t)grow * FO + c] = a;                            // mu
      else        out[(size_t)NN * FO + (size_t)grow * FO + (c - FO)] = a;   // logstd
    }
  }
}

// ---------------- launch ----------------

extern "C" void kernel_launch(void* const* d_in, const int* in_sizes, int n_in,
                              void* d_out, int out_size, void* d_ws, size_t ws_size,
                              hipStream_t stream) {
  const float* x   = (const float*)d_in[0];
  const int*   ei  = (const int*)d_in[1];   // [2, NE] flat: src then dst
  const float* W1  = (const float*)d_in[2];
  const float* b1  = (const float*)d_in[3];
  const float* Wmu = (const float*)d_in[4];
  const float* bmu = (const float*)d_in[5];
  const float* Wls = (const float*)d_in[6];
  const float* bls = (const float*)d_in[7];
  float* out = (float*)d_out;

  const int* src = ei;
  const int* dst = ei + NE;

  // workspace layout (~46 MB, all 16B-aligned)
  char* base = (char*)d_ws;
  int*   csr    = (int*)base;                          // NE*4 = 6.4 MB
  float* t1     = (float*)(base + (size_t)NE * 4);     // NN*FH*4 = 19.2 MB
  float* h      = t1 + (size_t)NN * FH;                // 19.2 MB
  int*   deg_i  = (int*)(h + (size_t)NN * FH);         // NN
  float* dinv   = (float*)(deg_i + NN);                // NN
  int*   off    = (int*)(dinv + NN);                   // NN+1
  int*   cursor = off + NN + 1;                        // NN
  int*   bsum   = cursor + NN;                         // NB

  // CSR build
  k_zero <<<(NN + 255) / 256, 256, 0, stream>>>(deg_i);
  k_hist <<<(NE + 255) / 256, 256, 0, stream>>>(dst, deg_i);
  k_scan1<<<NB, 256, 0, stream>>>(deg_i, bsum, dinv);
  k_scan2<<<1, 64, 0, stream>>>(bsum, off);
  k_scan3<<<NB, 256, 0, stream>>>(deg_i, bsum, off, cursor);
  k_bin  <<<(NE + 255) / 256, 256, 0, stream>>>(src, dst, cursor, csr);

  // layer 1: t1 = x@W1 ; h = relu(Ahat*t1 + b1)
  k_gemm1<<<(NN + 63) / 64, 256, 0, stream>>>(x, W1, t1);
  k_gather1<<<(NN + NODES_PER_BLOCK - 1) / NODES_PER_BLOCK, 256, 0, stream>>>(off, csr, t1, dinv, b1, h);

  // layer 2 fused: out = (Ahat*h)@[Wmu|Wls] + [bmu|bls]
  k_gather_gemm2<<<(NN + NODES_PER_BLOCK - 1) / NODES_PER_BLOCK, 256, 0, stream>>>(
      off, csr, h, dinv, Wmu, bmu, Wls, bls, out);
}

// Round 5
// 336.350 us; speedup vs baseline: 1.4311x; 1.4311x over previous
//
#include <hip/hip_runtime.h>

#define NN 100000
#define NE 1600000
#define FIN 128
#define FH 48
#define FO 32
#define NODES_PER_BLOCK 21          // gather: 12 threads/node, 252 of 256 active

// ---- partition parameters ----
#define LB 7                        // log2 nodes per coarse bucket
#define BKT_NODES 128               // nodes per bucket
#define NBKT ((NN + BKT_NODES - 1) / BKT_NODES)   // 782
#define PBLK 256                    // partition blocks
#define EPB (NE / PBLK)             // 6250 edges per partition block (exact)

// ================= CSR build: block-ranked two-level partition =================

// P1a: per-block coarse-bucket histogram -> H[blk][NBKT] (coalesced row write)
__global__ __launch_bounds__(256) void p1_hist(const int* __restrict__ dst, int* __restrict__ H) {
  __shared__ int hist[NBKT];
  const int t = threadIdx.x, blk = blockIdx.x;
  for (int i = t; i < NBKT; i += 256) hist[i] = 0;
  __syncthreads();
  const int e0 = blk * EPB;
  for (int k = t; k < EPB; k += 256) atomicAdd(&hist[dst[e0 + k] >> LB], 1);
  __syncthreads();
  for (int i = t; i < NBKT; i += 256) H[blk * NBKT + i] = hist[i];
}

// P1b: in-place column prefix: H[blk][b] := sum_{blk'<blk} H[blk'][b]; tot[b] = column total
// (H layout [blk][b] -> reads coalesced across threads at each blk step)
__global__ __launch_bounds__(256) void p1_colscan(int* __restrict__ H, int* __restrict__ tot) {
  int b = blockIdx.x * 256 + threadIdx.x;
  if (b >= NBKT) return;
  int run = 0;
  for (int blk = 0; blk < PBLK; ++blk) {
    int v = H[blk * NBKT + b];
    H[blk * NBKT + b] = run;
    run += v;
  }
  tot[b] = run;
}

// P1c: exclusive scan of tot[NBKT] -> base[NBKT+1]; also off[NN] = NE
__global__ __launch_bounds__(256) void p1_scan(const int* __restrict__ tot, int* __restrict__ base,
                                               int* __restrict__ off) {
  __shared__ int s[256];
  const int t = threadIdx.x;
  int c[4]; int sum = 0;
  #pragma unroll
  for (int k = 0; k < 4; ++k) {
    int idx = 4 * t + k;
    c[k] = (idx < NBKT) ? tot[idx] : 0;
    sum += c[k];
  }
  s[t] = sum;
  __syncthreads();
  for (int o = 1; o < 256; o <<= 1) {
    int v = (t >= o) ? s[t - o] : 0;
    __syncthreads();
    s[t] += v;
    __syncthreads();
  }
  int run = s[t] - sum;  // exclusive prefix of this thread's chunk
  #pragma unroll
  for (int k = 0; k < 4; ++k) {
    int idx = 4 * t + k;
    if (idx < NBKT) base[idx] = run;
    run += c[k];
  }
  if (t == 255) { base[NBKT] = run; off[NN] = run; }  // run == NE
}

// P1d: ranked scatter. Each block writes into exclusive sub-ranges -> no cross-XCD
// line ping-pong. Entry packs local_dst (7b) | src (17b).
__global__ __launch_bounds__(256) void p1_scatter(const int* __restrict__ src, const int* __restrict__ dst,
                                                  const int* __restrict__ H, const int* __restrict__ base,
                                                  int* __restrict__ pairs) {
  __shared__ int cur[NBKT];
  const int t = threadIdx.x, blk = blockIdx.x;
  for (int i = t; i < NBKT; i += 256) cur[i] = base[i] + H[blk * NBKT + i];
  __syncthreads();
  const int e0 = blk * EPB;
  for (int k = t; k < EPB; k += 256) {
    int d = dst[e0 + k];
    int s = src[e0 + k];
    int b = d >> LB;
    int pos = atomicAdd(&cur[b], 1);
    pairs[pos] = s | ((d & (BKT_NODES - 1)) << 17);
  }
}

// P2: per-bucket counting sort (one block per bucket; 8 KB XCD-local window).
// Produces csr (src only), off, dinv.
__global__ __launch_bounds__(256) void p2_bucket(const int* __restrict__ pairs, const int* __restrict__ base,
                                                 int* __restrict__ csr, int* __restrict__ off,
                                                 float* __restrict__ dinv) {
  __shared__ int cnt[BKT_NODES];
  __shared__ int s[BKT_NODES];
  const int t = threadIdx.x, b = blockIdx.x;
  const int j0 = base[b], j1 = base[b + 1];
  if (t < BKT_NODES) cnt[t] = 0;
  __syncthreads();
  for (int j = j0 + t; j < j1; j += 256) atomicAdd(&cnt[pairs[j] >> 17], 1);
  __syncthreads();
  int myc = 0;
  if (t < BKT_NODES) { myc = cnt[t]; s[t] = myc; }
  __syncthreads();
  for (int o = 1; o < BKT_NODES; o <<= 1) {
    int v = (t >= o && t < BKT_NODES) ? s[t - o] : 0;
    __syncthreads();
    if (t < BKT_NODES) s[t] += v;
    __syncthreads();
  }
  int loc = 0;
  if (t < BKT_NODES) loc = s[t] - myc;  // exclusive within bucket
  const int n = b * BKT_NODES + t;
  if (t < BKT_NODES && n < NN) {
    off[n] = j0 + loc;
    dinv[n] = rsqrtf((float)myc + 1.0f);  // +1 self-loop
  }
  __syncthreads();
  if (t < BKT_NODES) s[t] = loc;  // repurpose as bump cursor
  __syncthreads();
  for (int j = j0 + t; j < j1; j += 256) {
    int p = pairs[j];
    int pos = atomicAdd(&s[p >> 17], 1);
    csr[j0 + pos] = p & 0x1FFFF;
  }
}

// ================= layer-1 dense: t1 = x @ W1 =================

__global__ __launch_bounds__(256) void k_gemm1(const float* __restrict__ x, const float* __restrict__ W1,
                                               float* __restrict__ t1) {
  __shared__ float xs[64][132];
  __shared__ float ws[FIN][FH];
  const int t = threadIdx.x;
  const int row0 = blockIdx.x * 64;

  for (int i = t; i < FIN * FH; i += 256) ws[i / FH][i % FH] = W1[i];
  for (int i = t; i < 64 * (FIN / 4); i += 256) {
    int r = i >> 5, c4 = i & 31;
    float4 v = make_float4(0.f, 0.f, 0.f, 0.f);
    if (row0 + r < NN) v = ((const float4*)x)[(size_t)(row0 + r) * (FIN / 4) + c4];
    xs[r][c4 * 4 + 0] = v.x; xs[r][c4 * 4 + 1] = v.y;
    xs[r][c4 * 4 + 2] = v.z; xs[r][c4 * 4 + 3] = v.w;
  }
  __syncthreads();

  const int row = t >> 2;
  const int cg  = (t & 3) * 12;
  float acc[12];
  #pragma unroll
  for (int j = 0; j < 12; ++j) acc[j] = 0.f;

  #pragma unroll 4
  for (int k = 0; k < FIN; ++k) {
    float xv = xs[row][k];
    const float4* wp = (const float4*)&ws[k][cg];
    float4 w0 = wp[0], w1 = wp[1], w2 = wp[2];
    acc[0] += xv * w0.x; acc[1] += xv * w0.y; acc[2]  += xv * w0.z; acc[3]  += xv * w0.w;
    acc[4] += xv * w1.x; acc[5] += xv * w1.y; acc[6]  += xv * w1.z; acc[7]  += xv * w1.w;
    acc[8] += xv * w2.x; acc[9] += xv * w2.y; acc[10] += xv * w2.z; acc[11] += xv * w2.w;
  }

  const int grow = row0 + row;
  if (grow < NN) {
    float* tp = t1 + (size_t)grow * FH + cg;
    #pragma unroll
    for (int j = 0; j < 12; ++j) tp[j] = acc[j];
  }
}

// ================= layer-1 gather: h = relu(Ahat*t1 + b1) =================

__global__ __launch_bounds__(256) void k_gather1(const int* __restrict__ off, const int* __restrict__ csr,
                                                 const float* __restrict__ feat, const float* __restrict__ dinv,
                                                 const float* __restrict__ bias, float* __restrict__ out) {
  const int t = threadIdx.x;
  if (t >= NODES_PER_BLOCK * 12) return;
  const int local = t / 12;
  const int f4 = t - local * 12;
  const int node = blockIdx.x * NODES_PER_BLOCK + local;
  if (node >= NN) return;

  const float4* feat4 = (const float4*)feat;
  const float di = dinv[node];
  const float sn = di * di;
  float4 v = feat4[(size_t)node * 12 + f4];
  float4 acc = make_float4(v.x * sn, v.y * sn, v.z * sn, v.w * sn);

  int j = off[node];
  const int jend = off[node + 1];
  for (; j + 4 <= jend; j += 4) {
    int s0 = csr[j], s1 = csr[j + 1], s2 = csr[j + 2], s3 = csr[j + 3];
    float n0 = dinv[s0] * di, n1 = dinv[s1] * di, n2 = dinv[s2] * di, n3 = dinv[s3] * di;
    float4 v0 = feat4[(size_t)s0 * 12 + f4];
    float4 v1 = feat4[(size_t)s1 * 12 + f4];
    float4 v2 = feat4[(size_t)s2 * 12 + f4];
    float4 v3 = feat4[(size_t)s3 * 12 + f4];
    acc.x += n0 * v0.x; acc.y += n0 * v0.y; acc.z += n0 * v0.z; acc.w += n0 * v0.w;
    acc.x += n1 * v1.x; acc.y += n1 * v1.y; acc.z += n1 * v1.z; acc.w += n1 * v1.w;
    acc.x += n2 * v2.x; acc.y += n2 * v2.y; acc.z += n2 * v2.z; acc.w += n2 * v2.w;
    acc.x += n3 * v3.x; acc.y += n3 * v3.y; acc.z += n3 * v3.z; acc.w += n3 * v3.w;
  }
  for (; j < jend; ++j) {
    int s = csr[j];
    float nv = dinv[s] * di;
    float4 vv = feat4[(size_t)s * 12 + f4];
    acc.x += nv * vv.x; acc.y += nv * vv.y; acc.z += nv * vv.z; acc.w += nv * vv.w;
  }

  const float4 bb = ((const float4*)bias)[f4];
  acc.x = fmaxf(acc.x + bb.x, 0.f);
  acc.y = fmaxf(acc.y + bb.y, 0.f);
  acc.z = fmaxf(acc.z + bb.z, 0.f);
  acc.w = fmaxf(acc.w + bb.w, 0.f);
  ((float4*)out)[(size_t)node * 12 + f4] = acc;
}

// ================= layer-2 fused: out = (Ahat*h)@[Wmu|Wls] + [bmu|bls] =================

__global__ __launch_bounds__(256) void k_gather_gemm2(const int* __restrict__ off, const int* __restrict__ csr,
                                                      const float* __restrict__ feat, const float* __restrict__ dinv,
                                                      const float* __restrict__ Wmu, const float* __restrict__ bmu,
                                                      const float* __restrict__ Wls, const float* __restrict__ bls,
                                                      float* __restrict__ out) {
  __shared__ float wall[FH][2 * FO];             // [48][64]
  __shared__ float as2[NODES_PER_BLOCK][FH + 1];
  const int t = threadIdx.x;

  for (int i = t; i < FH * 2 * FO; i += 256) {
    int k = i >> 6, c = i & 63;
    wall[k][c] = (c < FO) ? Wmu[k * FO + c] : Wls[k * FO + (c - FO)];
  }

  const int local = t / 12;
  const int f4 = t - local * 12;
  const int node = blockIdx.x * NODES_PER_BLOCK + local;
  const bool active = (local < NODES_PER_BLOCK) && (node < NN);

  if (active) {
    const float4* feat4 = (const float4*)feat;
    const float di = dinv[node];
    const float sn = di * di;
    float4 v = feat4[(size_t)node * 12 + f4];
    float4 acc = make_float4(v.x * sn, v.y * sn, v.z * sn, v.w * sn);

    int j = off[node];
    const int jend = off[node + 1];
    for (; j + 4 <= jend; j += 4) {
      int s0 = csr[j], s1 = csr[j + 1], s2 = csr[j + 2], s3 = csr[j + 3];
      float n0 = dinv[s0] * di, n1 = dinv[s1] * di, n2 = dinv[s2] * di, n3 = dinv[s3] * di;
      float4 v0 = feat4[(size_t)s0 * 12 + f4];
      float4 v1 = feat4[(size_t)s1 * 12 + f4];
      float4 v2 = feat4[(size_t)s2 * 12 + f4];
      float4 v3 = feat4[(size_t)s3 * 12 + f4];
      acc.x += n0 * v0.x; acc.y += n0 * v0.y; acc.z += n0 * v0.z; acc.w += n0 * v0.w;
      acc.x += n1 * v1.x; acc.y += n1 * v1.y; acc.z += n1 * v1.z; acc.w += n1 * v1.w;
      acc.x += n2 * v2.x; acc.y += n2 * v2.y; acc.z += n2 * v2.z; acc.w += n2 * v2.w;
      acc.x += n3 * v3.x; acc.y += n3 * v3.y; acc.z += n3 * v3.z; acc.w += n3 * v3.w;
    }
    for (; j < jend; ++j) {
      int s = csr[j];
      float nv = dinv[s] * di;
      float4 vv = feat4[(size_t)s * 12 + f4];
      acc.x += nv * vv.x; acc.y += nv * vv.y; acc.z += nv * vv.z; acc.w += nv * vv.w;
    }

    float* ap = &as2[local][f4 * 4];
    ap[0] = acc.x; ap[1] = acc.y; ap[2] = acc.z; ap[3] = acc.w;
  }
  __syncthreads();

  for (int o = t; o < NODES_PER_BLOCK * 2 * FO; o += 256) {
    const int ln = o >> 6;
    const int c = o & 63;
    const int grow = blockIdx.x * NODES_PER_BLOCK + ln;
    if (grow < NN) {
      float a = (c < FO) ? bmu[c] : bls[c - FO];
      #pragma unroll
      for (int k = 0; k < FH; ++k) a += as2[ln][k] * wall[k][c];
      if (c < FO) out[(size_t)grow * FO + c] = a;
      else        out[(size_t)NN * FO + (size_t)grow * FO + (c - FO)] = a;
    }
  }
}

// ================= launch =================

extern "C" void kernel_launch(void* const* d_in, const int* in_sizes, int n_in,
                              void* d_out, int out_size, void* d_ws, size_t ws_size,
                              hipStream_t stream) {
  const float* x   = (const float*)d_in[0];
  const int*   ei  = (const int*)d_in[1];   // [2, NE] flat: src then dst
  const float* W1  = (const float*)d_in[2];
  const float* b1  = (const float*)d_in[3];
  const float* Wmu = (const float*)d_in[4];
  const float* bmu = (const float*)d_in[5];
  const float* Wls = (const float*)d_in[6];
  const float* bls = (const float*)d_in[7];
  float* out = (float*)d_out;

  const int* src = ei;
  const int* dst = ei + NE;

  // workspace layout (~52.5 MB, 16B-aligned where vector-accessed)
  char* base_p = (char*)d_ws;
  int*   pairs = (int*)base_p;                           // NE = 6.4 MB
  int*   csr   = pairs + (size_t)NE;                     // NE = 6.4 MB
  float* t1    = (float*)(csr + (size_t)NE);             // NN*FH = 19.2 MB
  float* h     = t1 + (size_t)NN * FH;                   // 19.2 MB
  int*   H     = (int*)(h + (size_t)NN * FH);            // PBLK*NBKT = 800 KB
  int*   tot   = H + (size_t)PBLK * NBKT;                // NBKT
  int*   bkb   = tot + NBKT;                             // NBKT+1 bucket bases
  int*   off   = bkb + NBKT + 1;                         // NN+1
  float* dinv  = (float*)(off + NN + 1);                 // NN

  // CSR build (block-ranked two-level partition)
  p1_hist   <<<PBLK, 256, 0, stream>>>(dst, H);
  p1_colscan<<<(NBKT + 255) / 256, 256, 0, stream>>>(H, tot);
  p1_scan   <<<1, 256, 0, stream>>>(tot, bkb, off);
  p1_scatter<<<PBLK, 256, 0, stream>>>(src, dst, H, bkb, pairs);
  p2_bucket <<<NBKT, 256, 0, stream>>>(pairs, bkb, csr, off, dinv);

  // layer 1: t1 = x@W1 ; h = relu(Ahat*t1 + b1)
  k_gemm1<<<(NN + 63) / 64, 256, 0, stream>>>(x, W1, t1);
  k_gather1<<<(NN + NODES_PER_BLOCK - 1) / NODES_PER_BLOCK, 256, 0, stream>>>(off, csr, t1, dinv, b1, h);

  // layer 2 fused
  k_gather_gemm2<<<(NN + NODES_PER_BLOCK - 1) / NODES_PER_BLOCK, 256, 0, stream>>>(
      off, csr, h, dinv, Wmu, bmu, Wls, bls, out);
}

// Round 6
// 320.178 us; speedup vs baseline: 1.5034x; 1.0505x over previous
//
#include <hip/hip_runtime.h>

#define NN 100000
#define NE 1600000
#define FIN 128
#define FH 48
#define FO 32
#define NODES_PER_BLOCK 21          // gather: 12 threads/node, 252 of 256 active

// ---- partition parameters ----
#define LB 7                        // log2 nodes per coarse bucket
#define BKT_NODES 128               // nodes per bucket
#define NBKT ((NN + BKT_NODES - 1) / BKT_NODES)   // 782
#define PBLK 250                    // partition blocks (EPB*4B = 25600 B, 16B-aligned)
#define EPB (NE / PBLK)             // 6400 edges per partition block (exact)
#define EPB4 (EPB / 4)              // 1600 int4 per block
#define P2CAP 4096                  // LDS staging capacity (edges) in p2_bucket

// ================= CSR build: block-ranked two-level partition =================

// P1a: per-block coarse-bucket histogram -> H[blk][NBKT] (int4-vectorized read)
__global__ __launch_bounds__(256) void p1_hist(const int4* __restrict__ dst4, int* __restrict__ H) {
  __shared__ int hist[NBKT];
  const int t = threadIdx.x, blk = blockIdx.x;
  for (int i = t; i < NBKT; i += 256) hist[i] = 0;
  __syncthreads();
  const int k0 = blk * EPB4;
  for (int k = t; k < EPB4; k += 256) {
    int4 d = dst4[k0 + k];
    atomicAdd(&hist[d.x >> LB], 1);
    atomicAdd(&hist[d.y >> LB], 1);
    atomicAdd(&hist[d.z >> LB], 1);
    atomicAdd(&hist[d.w >> LB], 1);
  }
  __syncthreads();
  for (int i = t; i < NBKT; i += 256) H[blk * NBKT + i] = hist[i];
}

// P1b: column prefix in XCD-MAJOR block order (blocks blk%8==0 first, then 1, ...).
// Rationale: consecutive ranks -> same-XCD writers in p1_scatter, so adjacent
// sub-ranges of `pairs` share 64B lines only within one XCD's L2 (no ping-pong).
__global__ __launch_bounds__(256) void p1_colscan(int* __restrict__ H, int* __restrict__ tot) {
  int b = blockIdx.x * 256 + threadIdx.x;
  if (b >= NBKT) return;
  int run = 0;
  for (int xcd = 0; xcd < 8; ++xcd) {
    for (int blk = xcd; blk < PBLK; blk += 8) {
      int v = H[blk * NBKT + b];
      H[blk * NBKT + b] = run;
      run += v;
    }
  }
  tot[b] = run;
}

// P1c: exclusive scan of tot[NBKT] -> base[NBKT+1]; also off[NN] = NE
__global__ __launch_bounds__(256) void p1_scan(const int* __restrict__ tot, int* __restrict__ base,
                                               int* __restrict__ off) {
  __shared__ int s[256];
  const int t = threadIdx.x;
  int c[4]; int sum = 0;
  #pragma unroll
  for (int k = 0; k < 4; ++k) {
    int idx = 4 * t + k;
    c[k] = (idx < NBKT) ? tot[idx] : 0;
    sum += c[k];
  }
  s[t] = sum;
  __syncthreads();
  for (int o = 1; o < 256; o <<= 1) {
    int v = (t >= o) ? s[t - o] : 0;
    __syncthreads();
    s[t] += v;
    __syncthreads();
  }
  int run = s[t] - sum;
  #pragma unroll
  for (int k = 0; k < 4; ++k) {
    int idx = 4 * t + k;
    if (idx < NBKT) base[idx] = run;
    run += c[k];
  }
  if (t == 255) { base[NBKT] = run; off[NN] = run; }  // run == NE
}

// P1d: ranked scatter (int4-vectorized reads). Entry packs local_dst(7b)<<17 | src(17b).
__global__ __launch_bounds__(256) void p1_scatter(const int4* __restrict__ src4, const int4* __restrict__ dst4,
                                                  const int* __restrict__ H, const int* __restrict__ base,
                                                  int* __restrict__ pairs) {
  __shared__ int cur[NBKT];
  const int t = threadIdx.x, blk = blockIdx.x;
  for (int i = t; i < NBKT; i += 256) cur[i] = base[i] + H[blk * NBKT + i];
  __syncthreads();
  const int k0 = blk * EPB4;
  for (int k = t; k < EPB4; k += 256) {
    int4 s = src4[k0 + k];
    int4 d = dst4[k0 + k];
    int b0 = d.x >> LB, b1 = d.y >> LB, b2 = d.z >> LB, b3 = d.w >> LB;
    int p0 = atomicAdd(&cur[b0], 1);
    pairs[p0] = s.x | ((d.x & (BKT_NODES - 1)) << 17);
    int p1 = atomicAdd(&cur[b1], 1);
    pairs[p1] = s.y | ((d.y & (BKT_NODES - 1)) << 17);
    int p2 = atomicAdd(&cur[b2], 1);
    pairs[p2] = s.z | ((d.z & (BKT_NODES - 1)) << 17);
    int p3 = atomicAdd(&cur[b3], 1);
    pairs[p3] = s.w | ((d.w & (BKT_NODES - 1)) << 17);
  }
}

// P2: per-bucket counting sort; bucket staged once in LDS (fallback to global两-pass
// only if a bucket exceeds P2CAP — impossible-in-expectation, kept for correctness).
__global__ __launch_bounds__(256) void p2_bucket(const int* __restrict__ pairs, const int* __restrict__ base,
                                                 int* __restrict__ csr, int* __restrict__ off,
                                                 float* __restrict__ dinv) {
  __shared__ int stage[P2CAP];
  __shared__ int cnt[BKT_NODES];
  __shared__ int s[BKT_NODES];
  const int t = threadIdx.x, b = blockIdx.x;
  const int j0 = base[b], j1 = base[b + 1];
  const int ne = j1 - j0;
  const bool fits = (ne <= P2CAP);

  if (t < BKT_NODES) cnt[t] = 0;
  if (fits) {
    for (int j = t; j < ne; j += 256) stage[j] = pairs[j0 + j];
  }
  __syncthreads();
  if (fits) {
    for (int j = t; j < ne; j += 256) atomicAdd(&cnt[stage[j] >> 17], 1);
  } else {
    for (int j = j0 + t; j < j1; j += 256) atomicAdd(&cnt[pairs[j] >> 17], 1);
  }
  __syncthreads();
  int myc = 0;
  if (t < BKT_NODES) { myc = cnt[t]; s[t] = myc; }
  __syncthreads();
  for (int o = 1; o < BKT_NODES; o <<= 1) {
    int v = (t >= o && t < BKT_NODES) ? s[t - o] : 0;
    __syncthreads();
    if (t < BKT_NODES) s[t] += v;
    __syncthreads();
  }
  int loc = 0;
  if (t < BKT_NODES) loc = s[t] - myc;  // exclusive within bucket
  const int n = b * BKT_NODES + t;
  if (t < BKT_NODES && n < NN) {
    off[n] = j0 + loc;
    dinv[n] = rsqrtf((float)myc + 1.0f);  // +1 self-loop
  }
  __syncthreads();
  if (t < BKT_NODES) s[t] = loc;  // repurpose as bump cursor
  __syncthreads();
  if (fits) {
    for (int j = t; j < ne; j += 256) {
      int p = stage[j];
      int pos = atomicAdd(&s[p >> 17], 1);
      csr[j0 + pos] = p & 0x1FFFF;
    }
  } else {
    for (int j = j0 + t; j < j1; j += 256) {
      int p = pairs[j];
      int pos = atomicAdd(&s[p >> 17], 1);
      csr[j0 + pos] = p & 0x1FFFF;
    }
  }
}

// ================= layer-1 dense: t1 = x @ W1 =================

__global__ __launch_bounds__(256) void k_gemm1(const float* __restrict__ x, const float* __restrict__ W1,
                                               float* __restrict__ t1) {
  __shared__ float xs[64][132];
  __shared__ float ws[FIN][FH];
  const int t = threadIdx.x;
  const int row0 = blockIdx.x * 64;

  for (int i = t; i < FIN * FH; i += 256) ws[i / FH][i % FH] = W1[i];
  for (int i = t; i < 64 * (FIN / 4); i += 256) {
    int r = i >> 5, c4 = i & 31;
    float4 v = make_float4(0.f, 0.f, 0.f, 0.f);
    if (row0 + r < NN) v = ((const float4*)x)[(size_t)(row0 + r) * (FIN / 4) + c4];
    xs[r][c4 * 4 + 0] = v.x; xs[r][c4 * 4 + 1] = v.y;
    xs[r][c4 * 4 + 2] = v.z; xs[r][c4 * 4 + 3] = v.w;
  }
  __syncthreads();

  const int row = t >> 2;
  const int cg  = (t & 3) * 12;
  float acc[12];
  #pragma unroll
  for (int j = 0; j < 12; ++j) acc[j] = 0.f;

  #pragma unroll 4
  for (int k = 0; k < FIN; ++k) {
    float xv = xs[row][k];
    const float4* wp = (const float4*)&ws[k][cg];
    float4 w0 = wp[0], w1 = wp[1], w2 = wp[2];
    acc[0] += xv * w0.x; acc[1] += xv * w0.y; acc[2]  += xv * w0.z; acc[3]  += xv * w0.w;
    acc[4] += xv * w1.x; acc[5] += xv * w1.y; acc[6]  += xv * w1.z; acc[7]  += xv * w1.w;
    acc[8] += xv * w2.x; acc[9] += xv * w2.y; acc[10] += xv * w2.z; acc[11] += xv * w2.w;
  }

  const int grow = row0 + row;
  if (grow < NN) {
    float* tp = t1 + (size_t)grow * FH + cg;
    #pragma unroll
    for (int j = 0; j < 12; ++j) tp[j] = acc[j];
  }
}

// ================= layer-1 gather: h = relu(Ahat*t1 + b1) =================

__global__ __launch_bounds__(256) void k_gather1(const int* __restrict__ off, const int* __restrict__ csr,
                                                 const float* __restrict__ feat, const float* __restrict__ dinv,
                                                 const float* __restrict__ bias, float* __restrict__ out) {
  const int t = threadIdx.x;
  if (t >= NODES_PER_BLOCK * 12) return;
  const int local = t / 12;
  const int f4 = t - local * 12;
  const int node = blockIdx.x * NODES_PER_BLOCK + local;
  if (node >= NN) return;

  const float4* feat4 = (const float4*)feat;
  const float di = dinv[node];
  const float sn = di * di;
  float4 v = feat4[(size_t)node * 12 + f4];
  float4 acc = make_float4(v.x * sn, v.y * sn, v.z * sn, v.w * sn);

  int j = off[node];
  const int jend = off[node + 1];
  for (; j + 4 <= jend; j += 4) {
    int s0 = csr[j], s1 = csr[j + 1], s2 = csr[j + 2], s3 = csr[j + 3];
    float n0 = dinv[s0] * di, n1 = dinv[s1] * di, n2 = dinv[s2] * di, n3 = dinv[s3] * di;
    float4 v0 = feat4[(size_t)s0 * 12 + f4];
    float4 v1 = feat4[(size_t)s1 * 12 + f4];
    float4 v2 = feat4[(size_t)s2 * 12 + f4];
    float4 v3 = feat4[(size_t)s3 * 12 + f4];
    acc.x += n0 * v0.x; acc.y += n0 * v0.y; acc.z += n0 * v0.z; acc.w += n0 * v0.w;
    acc.x += n1 * v1.x; acc.y += n1 * v1.y; acc.z += n1 * v1.z; acc.w += n1 * v1.w;
    acc.x += n2 * v2.x; acc.y += n2 * v2.y; acc.z += n2 * v2.z; acc.w += n2 * v2.w;
    acc.x += n3 * v3.x; acc.y += n3 * v3.y; acc.z += n3 * v3.z; acc.w += n3 * v3.w;
  }
  for (; j < jend; ++j) {
    int s = csr[j];
    float nv = dinv[s] * di;
    float4 vv = feat4[(size_t)s * 12 + f4];
    acc.x += nv * vv.x; acc.y += nv * vv.y; acc.z += nv * vv.z; acc.w += nv * vv.w;
  }

  const float4 bb = ((const float4*)bias)[f4];
  acc.x = fmaxf(acc.x + bb.x, 0.f);
  acc.y = fmaxf(acc.y + bb.y, 0.f);
  acc.z = fmaxf(acc.z + bb.z, 0.f);
  acc.w = fmaxf(acc.w + bb.w, 0.f);
  ((float4*)out)[(size_t)node * 12 + f4] = acc;
}

// ================= layer-2 fused: out = (Ahat*h)@[Wmu|Wls] + [bmu|bls] =================

__global__ __launch_bounds__(256) void k_gather_gemm2(const int* __restrict__ off, const int* __restrict__ csr,
                                                      const float* __restrict__ feat, const float* __restrict__ dinv,
                                                      const float* __restrict__ Wmu, const float* __restrict__ bmu,
                                                      const float* __restrict__ Wls, const float* __restrict__ bls,
                                                      float* __restrict__ out) {
  __shared__ float wall[FH][2 * FO];             // [48][64]
  __shared__ float as2[NODES_PER_BLOCK][FH + 1];
  const int t = threadIdx.x;

  for (int i = t; i < FH * 2 * FO; i += 256) {
    int k = i >> 6, c = i & 63;
    wall[k][c] = (c < FO) ? Wmu[k * FO + c] : Wls[k * FO + (c - FO)];
  }

  const int local = t / 12;
  const int f4 = t - local * 12;
  const int node = blockIdx.x * NODES_PER_BLOCK + local;
  const bool active = (local < NODES_PER_BLOCK) && (node < NN);

  if (active) {
    const float4* feat4 = (const float4*)feat;
    const float di = dinv[node];
    const float sn = di * di;
    float4 v = feat4[(size_t)node * 12 + f4];
    float4 acc = make_float4(v.x * sn, v.y * sn, v.z * sn, v.w * sn);

    int j = off[node];
    const int jend = off[node + 1];
    for (; j + 4 <= jend; j += 4) {
      int s0 = csr[j], s1 = csr[j + 1], s2 = csr[j + 2], s3 = csr[j + 3];
      float n0 = dinv[s0] * di, n1 = dinv[s1] * di, n2 = dinv[s2] * di, n3 = dinv[s3] * di;
      float4 v0 = feat4[(size_t)s0 * 12 + f4];
      float4 v1 = feat4[(size_t)s1 * 12 + f4];
      float4 v2 = feat4[(size_t)s2 * 12 + f4];
      float4 v3 = feat4[(size_t)s3 * 12 + f4];
      acc.x += n0 * v0.x; acc.y += n0 * v0.y; acc.z += n0 * v0.z; acc.w += n0 * v0.w;
      acc.x += n1 * v1.x; acc.y += n1 * v1.y; acc.z += n1 * v1.z; acc.w += n1 * v1.w;
      acc.x += n2 * v2.x; acc.y += n2 * v2.y; acc.z += n2 * v2.z; acc.w += n2 * v2.w;
      acc.x += n3 * v3.x; acc.y += n3 * v3.y; acc.z += n3 * v3.z; acc.w += n3 * v3.w;
    }
    for (; j < jend; ++j) {
      int s = csr[j];
      float nv = dinv[s] * di;
      float4 vv = feat4[(size_t)s * 12 + f4];
      acc.x += nv * vv.x; acc.y += nv * vv.y; acc.z += nv * vv.z; acc.w += nv * vv.w;
    }

    float* ap = &as2[local][f4 * 4];
    ap[0] = acc.x; ap[1] = acc.y; ap[2] = acc.z; ap[3] = acc.w;
  }
  __syncthreads();

  for (int o = t; o < NODES_PER_BLOCK * 2 * FO; o += 256) {
    const int ln = o >> 6;
    const int c = o & 63;
    const int grow = blockIdx.x * NODES_PER_BLOCK + ln;
    if (grow < NN) {
      float a = (c < FO) ? bmu[c] : bls[c - FO];
      #pragma unroll
      for (int k = 0; k < FH; ++k) a += as2[ln][k] * wall[k][c];
      if (c < FO) out[(size_t)grow * FO + c] = a;
      else        out[(size_t)NN * FO + (size_t)grow * FO + (c - FO)] = a;
    }
  }
}

// ================= launch =================

extern "C" void kernel_launch(void* const* d_in, const int* in_sizes, int n_in,
                              void* d_out, int out_size, void* d_ws, size_t ws_size,
                              hipStream_t stream) {
  const float* x   = (const float*)d_in[0];
  const int*   ei  = (const int*)d_in[1];   // [2, NE] flat: src then dst
  const float* W1  = (const float*)d_in[2];
  const float* b1  = (const float*)d_in[3];
  const float* Wmu = (const float*)d_in[4];
  const float* bmu = (const float*)d_in[5];
  const float* Wls = (const float*)d_in[6];
  const float* bls = (const float*)d_in[7];
  float* out = (float*)d_out;

  const int4* src4 = (const int4*)ei;
  const int4* dst4 = (const int4*)(ei + NE);

  // workspace layout (~52.5 MB)
  char* base_p = (char*)d_ws;
  int*   pairs = (int*)base_p;                           // NE = 6.4 MB
  int*   csr   = pairs + (size_t)NE;                     // NE = 6.4 MB
  float* t1    = (float*)(csr + (size_t)NE);             // NN*FH = 19.2 MB
  float* h     = t1 + (size_t)NN * FH;                   // 19.2 MB
  int*   H     = (int*)(h + (size_t)NN * FH);            // PBLK*NBKT = 782 KB
  int*   tot   = H + (size_t)PBLK * NBKT;                // NBKT
  int*   bkb   = tot + NBKT;                             // NBKT+1 bucket bases
  int*   off   = bkb + NBKT + 1;                         // NN+1
  float* dinv  = (float*)(off + NN + 1);                 // NN

  // CSR build (block-ranked two-level partition, XCD-major ranking)
  p1_hist   <<<PBLK, 256, 0, stream>>>(dst4, H);
  p1_colscan<<<(NBKT + 255) / 256, 256, 0, stream>>>(H, tot);
  p1_scan   <<<1, 256, 0, stream>>>(tot, bkb, off);
  p1_scatter<<<PBLK, 256, 0, stream>>>(src4, dst4, H, bkb, pairs);
  p2_bucket <<<NBKT, 256, 0, stream>>>(pairs, bkb, csr, off, dinv);

  // layer 1: t1 = x@W1 ; h = relu(Ahat*t1 + b1)
  k_gemm1<<<(NN + 63) / 64, 256, 0, stream>>>(x, W1, t1);
  k_gather1<<<(NN + NODES_PER_BLOCK - 1) / NODES_PER_BLOCK, 256, 0, stream>>>(off, csr, t1, dinv, b1, h);

  // layer 2 fused
  k_gather_gemm2<<<(NN + NODES_PER_BLOCK - 1) / NODES_PER_BLOCK, 256, 0, stream>>>(
      off, csr, h, dinv, Wmu, bmu, Wls, bls, out);
}

// Round 7
// 292.335 us; speedup vs baseline: 1.6465x; 1.0952x over previous
//
#include <hip/hip_runtime.h>
#include <hip/hip_fp16.h>

#define NN 100000
#define NE 1600000
#define FIN 128
#define FH 48
#define FO 32
#define NODES_PER_BLOCK 21          // gather: 12 threads/node, 252 of 256 active

// ---- partition parameters ----
#define LB 7                        // log2 nodes per coarse bucket
#define BKT_NODES 128               // nodes per bucket
#define NBKT ((NN + BKT_NODES - 1) / BKT_NODES)   // 782
#define PBLK 250                    // partition blocks (EPB*4B = 25600 B, 16B-aligned)
#define EPB (NE / PBLK)             // 6400 edges per partition block (exact)
#define EPB4 (EPB / 4)              // 1600 int4 per block
#define P2CAP 4096                  // LDS staging capacity (edges) in p2_bucket

// fp16 pack/unpack helpers (storage fp16, arithmetic fp32)
__device__ inline float2 h2f2(unsigned int u) {
  __half2 h = __builtin_bit_cast(__half2, u);
  return __half22float2(h);
}
__device__ inline unsigned int f2h2(float a, float b) {
  __half2 h = __floats2half2_rn(a, b);
  return __builtin_bit_cast(unsigned int, h);
}

// ================= CSR build: block-ranked two-level partition =================

// P1a: per-block coarse-bucket histogram -> H[blk][NBKT] (int4-vectorized read)
__global__ __launch_bounds__(256) void p1_hist(const int4* __restrict__ dst4, int* __restrict__ H) {
  __shared__ int hist[NBKT];
  const int t = threadIdx.x, blk = blockIdx.x;
  for (int i = t; i < NBKT; i += 256) hist[i] = 0;
  __syncthreads();
  const int k0 = blk * EPB4;
  for (int k = t; k < EPB4; k += 256) {
    int4 d = dst4[k0 + k];
    atomicAdd(&hist[d.x >> LB], 1);
    atomicAdd(&hist[d.y >> LB], 1);
    atomicAdd(&hist[d.z >> LB], 1);
    atomicAdd(&hist[d.w >> LB], 1);
  }
  __syncthreads();
  for (int i = t; i < NBKT; i += 256) H[blk * NBKT + i] = hist[i];
}

// P1b: column prefix in XCD-MAJOR block order (same-XCD writers get adjacent
// sub-ranges in p1_scatter -> no cross-XCD 64B-line ping-pong).
__global__ __launch_bounds__(256) void p1_colscan(int* __restrict__ H, int* __restrict__ tot) {
  int b = blockIdx.x * 256 + threadIdx.x;
  if (b >= NBKT) return;
  int run = 0;
  for (int xcd = 0; xcd < 8; ++xcd) {
    for (int blk = xcd; blk < PBLK; blk += 8) {
      int v = H[blk * NBKT + b];
      H[blk * NBKT + b] = run;
      run += v;
    }
  }
  tot[b] = run;
}

// P1c: exclusive scan of tot[NBKT] -> base[NBKT+1]; also off[NN] = NE
__global__ __launch_bounds__(256) void p1_scan(const int* __restrict__ tot, int* __restrict__ base,
                                               int* __restrict__ off) {
  __shared__ int s[256];
  const int t = threadIdx.x;
  int c[4]; int sum = 0;
  #pragma unroll
  for (int k = 0; k < 4; ++k) {
    int idx = 4 * t + k;
    c[k] = (idx < NBKT) ? tot[idx] : 0;
    sum += c[k];
  }
  s[t] = sum;
  __syncthreads();
  for (int o = 1; o < 256; o <<= 1) {
    int v = (t >= o) ? s[t - o] : 0;
    __syncthreads();
    s[t] += v;
    __syncthreads();
  }
  int run = s[t] - sum;
  #pragma unroll
  for (int k = 0; k < 4; ++k) {
    int idx = 4 * t + k;
    if (idx < NBKT) base[idx] = run;
    run += c[k];
  }
  if (t == 255) { base[NBKT] = run; off[NN] = run; }  // run == NE
}

// P1d: ranked scatter (int4-vectorized reads). Entry packs local_dst(7b)<<17 | src(17b).
__global__ __launch_bounds__(256) void p1_scatter(const int4* __restrict__ src4, const int4* __restrict__ dst4,
                                                  const int* __restrict__ H, const int* __restrict__ base,
                                                  int* __restrict__ pairs) {
  __shared__ int cur[NBKT];
  const int t = threadIdx.x, blk = blockIdx.x;
  for (int i = t; i < NBKT; i += 256) cur[i] = base[i] + H[blk * NBKT + i];
  __syncthreads();
  const int k0 = blk * EPB4;
  for (int k = t; k < EPB4; k += 256) {
    int4 s = src4[k0 + k];
    int4 d = dst4[k0 + k];
    int b0 = d.x >> LB, b1 = d.y >> LB, b2 = d.z >> LB, b3 = d.w >> LB;
    int p0 = atomicAdd(&cur[b0], 1);
    pairs[p0] = s.x | ((d.x & (BKT_NODES - 1)) << 17);
    int p1 = atomicAdd(&cur[b1], 1);
    pairs[p1] = s.y | ((d.y & (BKT_NODES - 1)) << 17);
    int p2 = atomicAdd(&cur[b2], 1);
    pairs[p2] = s.z | ((d.z & (BKT_NODES - 1)) << 17);
    int p3 = atomicAdd(&cur[b3], 1);
    pairs[p3] = s.w | ((d.w & (BKT_NODES - 1)) << 17);
  }
}

// P2: per-bucket counting sort; bucket staged once in LDS (global fallback only
// if a bucket exceeds P2CAP — kept for correctness).
__global__ __launch_bounds__(256) void p2_bucket(const int* __restrict__ pairs, const int* __restrict__ base,
                                                 int* __restrict__ csr, int* __restrict__ off,
                                                 float* __restrict__ dinv) {
  __shared__ int stage[P2CAP];
  __shared__ int cnt[BKT_NODES];
  __shared__ int s[BKT_NODES];
  const int t = threadIdx.x, b = blockIdx.x;
  const int j0 = base[b], j1 = base[b + 1];
  const int ne = j1 - j0;
  const bool fits = (ne <= P2CAP);

  if (t < BKT_NODES) cnt[t] = 0;
  if (fits) {
    for (int j = t; j < ne; j += 256) stage[j] = pairs[j0 + j];
  }
  __syncthreads();
  if (fits) {
    for (int j = t; j < ne; j += 256) atomicAdd(&cnt[stage[j] >> 17], 1);
  } else {
    for (int j = j0 + t; j < j1; j += 256) atomicAdd(&cnt[pairs[j] >> 17], 1);
  }
  __syncthreads();
  int myc = 0;
  if (t < BKT_NODES) { myc = cnt[t]; s[t] = myc; }
  __syncthreads();
  for (int o = 1; o < BKT_NODES; o <<= 1) {
    int v = (t >= o && t < BKT_NODES) ? s[t - o] : 0;
    __syncthreads();
    if (t < BKT_NODES) s[t] += v;
    __syncthreads();
  }
  int loc = 0;
  if (t < BKT_NODES) loc = s[t] - myc;  // exclusive within bucket
  const int n = b * BKT_NODES + t;
  if (t < BKT_NODES && n < NN) {
    off[n] = j0 + loc;
    dinv[n] = rsqrtf((float)myc + 1.0f);  // +1 self-loop
  }
  __syncthreads();
  if (t < BKT_NODES) s[t] = loc;  // repurpose as bump cursor
  __syncthreads();
  if (fits) {
    for (int j = t; j < ne; j += 256) {
      int p = stage[j];
      int pos = atomicAdd(&s[p >> 17], 1);
      csr[j0 + pos] = p & 0x1FFFF;
    }
  } else {
    for (int j = j0 + t; j < j1; j += 256) {
      int p = pairs[j];
      int pos = atomicAdd(&s[p >> 17], 1);
      csr[j0 + pos] = p & 0x1FFFF;
    }
  }
}

// ================= layer-1 dense: t1h = fp16(x @ W1) =================

__global__ __launch_bounds__(256) void k_gemm1(const float* __restrict__ x, const float* __restrict__ W1,
                                               __half* __restrict__ t1h) {
  __shared__ float xs[64][132];
  __shared__ float ws[FIN][FH];
  const int t = threadIdx.x;
  const int row0 = blockIdx.x * 64;

  for (int i = t; i < FIN * FH; i += 256) ws[i / FH][i % FH] = W1[i];
  for (int i = t; i < 64 * (FIN / 4); i += 256) {
    int r = i >> 5, c4 = i & 31;
    float4 v = make_float4(0.f, 0.f, 0.f, 0.f);
    if (row0 + r < NN) v = ((const float4*)x)[(size_t)(row0 + r) * (FIN / 4) + c4];
    xs[r][c4 * 4 + 0] = v.x; xs[r][c4 * 4 + 1] = v.y;
    xs[r][c4 * 4 + 2] = v.z; xs[r][c4 * 4 + 3] = v.w;
  }
  __syncthreads();

  const int row = t >> 2;
  const int cg  = (t & 3) * 12;
  float acc[12];
  #pragma unroll
  for (int j = 0; j < 12; ++j) acc[j] = 0.f;

  #pragma unroll 4
  for (int k = 0; k < FIN; ++k) {
    float xv = xs[row][k];
    const float4* wp = (const float4*)&ws[k][cg];
    float4 w0 = wp[0], w1 = wp[1], w2 = wp[2];
    acc[0] += xv * w0.x; acc[1] += xv * w0.y; acc[2]  += xv * w0.z; acc[3]  += xv * w0.w;
    acc[4] += xv * w1.x; acc[5] += xv * w1.y; acc[6]  += xv * w1.z; acc[7]  += xv * w1.w;
    acc[8] += xv * w2.x; acc[9] += xv * w2.y; acc[10] += xv * w2.z; acc[11] += xv * w2.w;
  }

  const int grow = row0 + row;
  if (grow < NN) {
    uint2* p = (uint2*)(t1h + (size_t)grow * FH + cg);  // byte off = cg*2 ∈ {0,24,48,72}, 8B-aligned
    p[0] = make_uint2(f2h2(acc[0], acc[1]), f2h2(acc[2],  acc[3]));
    p[1] = make_uint2(f2h2(acc[4], acc[5]), f2h2(acc[6],  acc[7]));
    p[2] = make_uint2(f2h2(acc[8], acc[9]), f2h2(acc[10], acc[11]));
  }
}

// ================= layer-1 gather: h16 = fp16(relu(Ahat*t1 + b1)) =================
// 12 lanes/node; each lane owns 4 halves (uint2 load), fp32 accumulate.

__global__ __launch_bounds__(256) void k_gather1(const int* __restrict__ off, const int* __restrict__ csr,
                                                 const __half* __restrict__ feat16, const float* __restrict__ dinv,
                                                 const float* __restrict__ bias, __half* __restrict__ out16) {
  const int t = threadIdx.x;
  if (t >= NODES_PER_BLOCK * 12) return;
  const int local = t / 12;
  const int f4 = t - local * 12;
  const int node = blockIdx.x * NODES_PER_BLOCK + local;
  if (node >= NN) return;

  const uint2* feat8 = (const uint2*)feat16;   // 4 halves per uint2, 12 per row
  const float di = dinv[node];
  const float sn = di * di;
  uint2 rs = feat8[(size_t)node * 12 + f4];
  float2 s01 = h2f2(rs.x), s23 = h2f2(rs.y);
  float4 acc = make_float4(s01.x * sn, s01.y * sn, s23.x * sn, s23.y * sn);

  int j = off[node];
  const int jend = off[node + 1];
  for (; j + 4 <= jend; j += 4) {
    int s0 = csr[j], s1 = csr[j + 1], s2 = csr[j + 2], s3 = csr[j + 3];
    float n0 = dinv[s0] * di, n1 = dinv[s1] * di, n2 = dinv[s2] * di, n3 = dinv[s3] * di;
    uint2 r0 = feat8[(size_t)s0 * 12 + f4];
    uint2 r1 = feat8[(size_t)s1 * 12 + f4];
    uint2 r2 = feat8[(size_t)s2 * 12 + f4];
    uint2 r3 = feat8[(size_t)s3 * 12 + f4];
    float2 a0 = h2f2(r0.x), b0 = h2f2(r0.y);
    float2 a1 = h2f2(r1.x), b1v = h2f2(r1.y);
    float2 a2 = h2f2(r2.x), b2 = h2f2(r2.y);
    float2 a3 = h2f2(r3.x), b3 = h2f2(r3.y);
    acc.x += n0 * a0.x; acc.y += n0 * a0.y; acc.z += n0 * b0.x; acc.w += n0 * b0.y;
    acc.x += n1 * a1.x; acc.y += n1 * a1.y; acc.z += n1 * b1v.x; acc.w += n1 * b1v.y;
    acc.x += n2 * a2.x; acc.y += n2 * a2.y; acc.z += n2 * b2.x; acc.w += n2 * b2.y;
    acc.x += n3 * a3.x; acc.y += n3 * a3.y; acc.z += n3 * b3.x; acc.w += n3 * b3.y;
  }
  for (; j < jend; ++j) {
    int s = csr[j];
    float nv = dinv[s] * di;
    uint2 r = feat8[(size_t)s * 12 + f4];
    float2 a = h2f2(r.x), b = h2f2(r.y);
    acc.x += nv * a.x; acc.y += nv * a.y; acc.z += nv * b.x; acc.w += nv * b.y;
  }

  const float4 bb = ((const float4*)bias)[f4];
  acc.x = fmaxf(acc.x + bb.x, 0.f);
  acc.y = fmaxf(acc.y + bb.y, 0.f);
  acc.z = fmaxf(acc.z + bb.z, 0.f);
  acc.w = fmaxf(acc.w + bb.w, 0.f);
  ((uint2*)out16)[(size_t)node * 12 + f4] = make_uint2(f2h2(acc.x, acc.y), f2h2(acc.z, acc.w));
}

// ================= layer-2 fused: out = (Ahat*h)@[Wmu|Wls] + [bmu|bls] =================

__global__ __launch_bounds__(256) void k_gather_gemm2(const int* __restrict__ off, const int* __restrict__ csr,
                                                      const __half* __restrict__ feat16, const float* __restrict__ dinv,
                                                      const float* __restrict__ Wmu, const float* __restrict__ bmu,
                                                      const float* __restrict__ Wls, const float* __restrict__ bls,
                                                      float* __restrict__ out) {
  __shared__ float wall[FH][2 * FO];             // [48][64]
  __shared__ float as2[NODES_PER_BLOCK][FH + 1];
  const int t = threadIdx.x;

  for (int i = t; i < FH * 2 * FO; i += 256) {
    int k = i >> 6, c = i & 63;
    wall[k][c] = (c < FO) ? Wmu[k * FO + c] : Wls[k * FO + (c - FO)];
  }

  const int local = t / 12;
  const int f4 = t - local * 12;
  const int node = blockIdx.x * NODES_PER_BLOCK + local;
  const bool active = (local < NODES_PER_BLOCK) && (node < NN);

  if (active) {
    const uint2* feat8 = (const uint2*)feat16;
    const float di = dinv[node];
    const float sn = di * di;
    uint2 rs = feat8[(size_t)node * 12 + f4];
    float2 s01 = h2f2(rs.x), s23 = h2f2(rs.y);
    float4 acc = make_float4(s01.x * sn, s01.y * sn, s23.x * sn, s23.y * sn);

    int j = off[node];
    const int jend = off[node + 1];
    for (; j + 4 <= jend; j += 4) {
      int s0 = csr[j], s1 = csr[j + 1], s2 = csr[j + 2], s3 = csr[j + 3];
      float n0 = dinv[s0] * di, n1 = dinv[s1] * di, n2 = dinv[s2] * di, n3 = dinv[s3] * di;
      uint2 r0 = feat8[(size_t)s0 * 12 + f4];
      uint2 r1 = feat8[(size_t)s1 * 12 + f4];
      uint2 r2 = feat8[(size_t)s2 * 12 + f4];
      uint2 r3 = feat8[(size_t)s3 * 12 + f4];
      float2 a0 = h2f2(r0.x), b0 = h2f2(r0.y);
      float2 a1 = h2f2(r1.x), b1v = h2f2(r1.y);
      float2 a2 = h2f2(r2.x), b2 = h2f2(r2.y);
      float2 a3 = h2f2(r3.x), b3 = h2f2(r3.y);
      acc.x += n0 * a0.x; acc.y += n0 * a0.y; acc.z += n0 * b0.x; acc.w += n0 * b0.y;
      acc.x += n1 * a1.x; acc.y += n1 * a1.y; acc.z += n1 * b1v.x; acc.w += n1 * b1v.y;
      acc.x += n2 * a2.x; acc.y += n2 * a2.y; acc.z += n2 * b2.x; acc.w += n2 * b2.y;
      acc.x += n3 * a3.x; acc.y += n3 * a3.y; acc.z += n3 * b3.x; acc.w += n3 * b3.y;
    }
    for (; j < jend; ++j) {
      int s = csr[j];
      float nv = dinv[s] * di;
      uint2 r = feat8[(size_t)s * 12 + f4];
      float2 a = h2f2(r.x), b = h2f2(r.y);
      acc.x += nv * a.x; acc.y += nv * a.y; acc.z += nv * b.x; acc.w += nv * b.y;
    }

    float* ap = &as2[local][f4 * 4];
    ap[0] = acc.x; ap[1] = acc.y; ap[2] = acc.z; ap[3] = acc.w;
  }
  __syncthreads();

  for (int o = t; o < NODES_PER_BLOCK * 2 * FO; o += 256) {
    const int ln = o >> 6;
    const int c = o & 63;
    const int grow = blockIdx.x * NODES_PER_BLOCK + ln;
    if (grow < NN) {
      float a = (c < FO) ? bmu[c] : bls[c - FO];
      #pragma unroll
      for (int k = 0; k < FH; ++k) a += as2[ln][k] * wall[k][c];
      if (c < FO) out[(size_t)grow * FO + c] = a;
      else        out[(size_t)NN * FO + (size_t)grow * FO + (c - FO)] = a;
    }
  }
}

// ================= launch =================

extern "C" void kernel_launch(void* const* d_in, const int* in_sizes, int n_in,
                              void* d_out, int out_size, void* d_ws, size_t ws_size,
                              hipStream_t stream) {
  const float* x   = (const float*)d_in[0];
  const int*   ei  = (const int*)d_in[1];   // [2, NE] flat: src then dst
  const float* W1  = (const float*)d_in[2];
  const float* b1  = (const float*)d_in[3];
  const float* Wmu = (const float*)d_in[4];
  const float* bmu = (const float*)d_in[5];
  const float* Wls = (const float*)d_in[6];
  const float* bls = (const float*)d_in[7];
  float* out = (float*)d_out;

  const int4* src4 = (const int4*)ei;
  const int4* dst4 = (const int4*)(ei + NE);

  // workspace layout (~33 MB, 16B-aligned boundaries)
  char* base_p = (char*)d_ws;
  int*    pairs = (int*)base_p;                          // NE*4 = 6.4 MB
  int*    csr   = pairs + (size_t)NE;                    // 6.4 MB
  __half* t1h   = (__half*)(csr + (size_t)NE);           // NN*FH*2 = 9.6 MB
  __half* h16   = t1h + (size_t)NN * FH;                 // 9.6 MB
  int*    H     = (int*)(h16 + (size_t)NN * FH);         // PBLK*NBKT = 782 KB
  int*    tot   = H + (size_t)PBLK * NBKT;               // NBKT
  int*    bkb   = tot + NBKT;                            // NBKT+1
  int*    off   = bkb + NBKT + 1;                        // NN+1
  float*  dinv  = (float*)(off + NN + 1);                // NN

  // CSR build (block-ranked two-level partition, XCD-major ranking)
  p1_hist   <<<PBLK, 256, 0, stream>>>(dst4, H);
  p1_colscan<<<(NBKT + 255) / 256, 256, 0, stream>>>(H, tot);
  p1_scan   <<<1, 256, 0, stream>>>(tot, bkb, off);
  p1_scatter<<<PBLK, 256, 0, stream>>>(src4, dst4, H, bkb, pairs);
  p2_bucket <<<NBKT, 256, 0, stream>>>(pairs, bkb, csr, off, dinv);

  // layer 1: t1h = fp16(x@W1) ; h16 = fp16(relu(Ahat*t1 + b1))
  k_gemm1<<<(NN + 63) / 64, 256, 0, stream>>>(x, W1, t1h);
  k_gather1<<<(NN + NODES_PER_BLOCK - 1) / NODES_PER_BLOCK, 256, 0, stream>>>(off, csr, t1h, dinv, b1, h16);

  // layer 2 fused
  k_gather_gemm2<<<(NN + NODES_PER_BLOCK - 1) / NODES_PER_BLOCK, 256, 0, stream>>>(
      off, csr, h16, dinv, Wmu, bmu, Wls, bls, out);
}